// Round 1
// baseline (3386.642 us; speedup 1.0000x reference)
//
#include <hip/hip_runtime.h>
#include <hip/hip_bf16.h>

#define T_TOK 16384
#define DDIM  1024
#define NEXP  8
#define HDIM  4096

#define BM 128
#define BN 128
#define BK 64

typedef __attribute__((ext_vector_type(8))) short bf16x8;
typedef __attribute__((ext_vector_type(4))) float f32x4;

__device__ __forceinline__ unsigned short f2bf(float f) {
  unsigned int x = __builtin_bit_cast(unsigned int, f);
  x += 0x7fffu + ((x >> 16) & 1u);   // RNE
  return (unsigned short)(x >> 16);
}
__device__ __forceinline__ float bf2f(unsigned short u) {
  unsigned int x = ((unsigned int)u) << 16;
  return __builtin_bit_cast(float, x);
}
__device__ __forceinline__ void gload16(void* lds, const void* g) {
  __builtin_amdgcn_global_load_lds(
      (const __attribute__((address_space(1))) unsigned int*)g,
      (__attribute__((address_space(3))) unsigned int*)lds, 16, 0, 0);
}
__device__ __forceinline__ f32x4 mfma16(bf16x8 a, bf16x8 b, f32x4 c) {
  return __builtin_amdgcn_mfma_f32_16x16x32_bf16(a, b, c, 0, 0, 0);
}

// ---------------- workspace layout (bytes) ----------------
#define OFF_CNT    ((size_t)0)          // 8 int
#define OFF_OFFS   ((size_t)64)         // 8 int
#define OFF_CURS   ((size_t)128)        // 8 int
#define OFF_GWSUM  ((size_t)192)        // 8 float
#define OFF_TOPE   ((size_t)256)                          // T*2 int
#define OFF_TOPW   (OFF_TOPE + (size_t)T_TOK*2*4)         // T*2 float
#define OFF_ROWTOK (OFF_TOPW + (size_t)T_TOK*2*4)         // 2T int
#define OFF_ROWG   (OFF_ROWTOK + (size_t)T_TOK*2*4)       // 2T float
#define OFF_XG     ((size_t)1 << 20)                      // 2T x D bf16
#define OFF_W1B    (OFF_XG  + (size_t)2*T_TOK*DDIM*2)
#define OFF_W2B    (OFF_W1B + (size_t)HDIM*DDIM*2)
#define OFF_WPB    (OFF_W2B + (size_t)HDIM*DDIM*2)
#define OFF_ACT    (OFF_WPB + (size_t)HDIM*DDIM*2)        // T x H bf16
#define WS_NEEDED  (OFF_ACT + (size_t)T_TOK*HDIM*2)

// ---------------- gating ----------------
__global__ __launch_bounds__(256) void k_gate(
    const float* __restrict__ x, const float* __restrict__ noise,
    const float* __restrict__ gate_w, const float* __restrict__ nw,
    int* __restrict__ counts, float* __restrict__ gwsum,
    int* __restrict__ tope, float* __restrict__ topw)
{
  __shared__ float gw_s[NEXP * DDIM];     // 32 KB
  __shared__ float blk_gw[NEXP];
  __shared__ int   blk_cnt[NEXP];
  const int tid = threadIdx.x;
  if (tid < NEXP) { blk_gw[tid] = 0.f; blk_cnt[tid] = 0; }
  // stage gate_w into LDS
  {
    float4* dst = (float4*)gw_s;
    const float4* src = (const float4*)gate_w;
    for (int i = tid; i < NEXP * DDIM / 4; i += 256) dst[i] = src[i];
  }
  __syncthreads();

  const int wv = tid >> 6, lane = tid & 63;
  const int t = blockIdx.x * 4 + wv;

  // load x row (16 elems / lane as 4x float4)
  const float4* xr = (const float4*)(x + (size_t)t * DDIM);
  float4 xv[4];
  #pragma unroll
  for (int c = 0; c < 4; ++c) xv[c] = xr[lane + 64 * c];

  float logit[NEXP];
  #pragma unroll
  for (int e = 0; e < NEXP; ++e) {
    float p = 0.f;
    const float4* g4 = (const float4*)(gw_s + e * DDIM);
    #pragma unroll
    for (int c = 0; c < 4; ++c) {
      float4 g = g4[lane + 64 * c];
      p += xv[c].x * g.x + xv[c].y * g.y + xv[c].z * g.z + xv[c].w * g.w;
    }
    #pragma unroll
    for (int off = 32; off >= 1; off >>= 1) p += __shfl_xor(p, off, 64);
    logit[e] = p;
  }

  if (lane == 0) {
    float m = logit[0];
    #pragma unroll
    for (int e = 1; e < NEXP; ++e) m = fmaxf(m, logit[e]);
    float sm[NEXP]; float s = 0.f;
    #pragma unroll
    for (int e = 0; e < NEXP; ++e) { sm[e] = expf(logit[e] - m); s += sm[e]; }
    float inv = 1.f / s;
    #pragma unroll
    for (int e = 0; e < NEXP; ++e) atomicAdd(&blk_gw[e], sm[e] * inv);

    float ln[NEXP];
    #pragma unroll
    for (int e = 0; e < NEXP; ++e) ln[e] = logit[e] + noise[(size_t)t * NEXP + e] * nw[e];
    int i1 = 0; float v1 = ln[0];
    #pragma unroll
    for (int e = 1; e < NEXP; ++e) if (ln[e] > v1) { v1 = ln[e]; i1 = e; }
    int i2 = -1; float v2 = -3.4e38f;
    #pragma unroll
    for (int e = 0; e < NEXP; ++e) if (e != i1 && ln[e] > v2) { v2 = ln[e]; i2 = e; }
    float b = expf(v2 - v1);
    float wsum = 1.f + b;
    tope[2 * t] = i1; tope[2 * t + 1] = i2;
    topw[2 * t] = 1.f / wsum; topw[2 * t + 1] = b / wsum;
    atomicAdd(&blk_cnt[i1], 1); atomicAdd(&blk_cnt[i2], 1);
  }
  __syncthreads();
  if (tid < NEXP) {
    atomicAdd(&counts[tid], blk_cnt[tid]);
    atomicAdd(&gwsum[tid], blk_gw[tid]);
  }
}

__global__ void k_scan(const int* __restrict__ counts, int* __restrict__ offsets,
                       int* __restrict__ cursors) {
  if (threadIdx.x == 0) {
    int acc = 0;
    for (int e = 0; e < NEXP; ++e) { offsets[e] = acc; cursors[e] = acc; acc += counts[e]; }
  }
}

// scatter token rows into per-expert lists + gather x -> bf16
__global__ __launch_bounds__(256) void k_scatter(
    const float* __restrict__ x, const int* __restrict__ tope,
    const float* __restrict__ topw, int* __restrict__ cursors,
    int* __restrict__ rowtok, float* __restrict__ rowgate,
    unsigned short* __restrict__ Xg)
{
  const int tid = threadIdx.x;
  const int wv = tid >> 6, lane = tid & 63;
  const int t = blockIdx.x * 4 + wv;
  int r0 = 0, r1 = 0;
  if (lane == 0) {
    int e0 = tope[2 * t], e1 = tope[2 * t + 1];
    r0 = atomicAdd(&cursors[e0], 1);
    r1 = atomicAdd(&cursors[e1], 1);
    rowtok[r0] = t; rowtok[r1] = t;
    rowgate[r0] = topw[2 * t]; rowgate[r1] = topw[2 * t + 1];
  }
  r0 = __shfl(r0, 0, 64);
  r1 = __shfl(r1, 0, 64);
  const float4* xr = (const float4*)(x + (size_t)t * DDIM);
  ushort4 o[4];
  #pragma unroll
  for (int c = 0; c < 4; ++c) {
    float4 v = xr[lane + 64 * c];
    o[c].x = f2bf(v.x); o[c].y = f2bf(v.y); o[c].z = f2bf(v.z); o[c].w = f2bf(v.w);
  }
  ushort4* d0 = (ushort4*)(Xg + (size_t)r0 * DDIM);
  ushort4* d1 = (ushort4*)(Xg + (size_t)r1 * DDIM);
  #pragma unroll
  for (int c = 0; c < 4; ++c) d0[lane + 64 * c] = o[c];
  #pragma unroll
  for (int c = 0; c < 4; ++c) d1[lane + 64 * c] = o[c];
}

// fp32 -> bf16 cast of one expert's three weight matrices
__global__ __launch_bounds__(256) void k_cast(
    const float* __restrict__ s1, const float* __restrict__ s2,
    const float* __restrict__ s3, unsigned short* __restrict__ d1,
    unsigned short* __restrict__ d2, unsigned short* __restrict__ d3, int n_each)
{
  const int n4 = n_each / 4;
  for (int i = blockIdx.x * blockDim.x + threadIdx.x; i < 3 * n4;
       i += gridDim.x * blockDim.x) {
    const float* s; unsigned short* d; int j = i;
    if (j < n4)            { s = s1; d = d1; }
    else if (j < 2 * n4)   { s = s2; d = d2; j -= n4; }
    else                   { s = s3; d = d3; j -= 2 * n4; }
    float4 v = ((const float4*)s)[j];
    ushort4 o;
    o.x = f2bf(v.x); o.y = f2bf(v.y); o.z = f2bf(v.z); o.w = f2bf(v.w);
    ((ushort4*)d)[j] = o;
  }
}

// ---------------- GEMM: C[m,n] = sum_k A[m,k]*B[n,k]  (both row-major, K contiguous)
// EPI 0: act[lr,n] = bf16(acc + b1[n])
// EPI 1: act[lr,n] = bf16( h * silu(acc + b2[n]) )   (h = previous act value)
// EPI 2: Y[tok,n] += gate * (acc + bp[n])            (serialized across experts)
template<int EPI>
__global__ __launch_bounds__(256) void k_gemm(
    const unsigned short* __restrict__ Ab, const unsigned short* __restrict__ Bw,
    int K, int N,
    const int* __restrict__ counts, const int* __restrict__ offsets, int e,
    unsigned short* __restrict__ Cact, const float* __restrict__ bias,
    const int* __restrict__ rowtok, const float* __restrict__ rowgate,
    float* __restrict__ Y)
{
  const int cnt = counts[e];
  if (cnt <= 0) return;
  const int m0 = blockIdx.x * BM;
  if (m0 >= cnt) return;
  const int n0 = blockIdx.y * BN;
  const int off = offsets[e];
  const unsigned short* A = (EPI == 2) ? Ab : (Ab + (size_t)off * K);

  __shared__ unsigned short As[BM * BK];  // 16 KB
  __shared__ unsigned short Bs[BN * BK];  // 16 KB

  const int tid = threadIdx.x;
  const int wid = tid >> 6, lane = tid & 63;
  const int wr = wid >> 1, wc = wid & 1;          // 2x2 waves of 64x64
  const int fr  = lane & 15;
  const int fkb = (lane >> 4) * 8;                // k-element offset

  f32x4 acc[4][4] = {};

  const int nsteps = K / BK;
  for (int kt = 0; kt < nsteps; ++kt) {
    const int k0 = kt * BK;
    // stage A and B tiles: 1024 x 16B segments each, 4 per thread
    #pragma unroll
    for (int it = 0; it < 4; ++it) {
      int idx = it * 256 + tid;
      int row = idx >> 3, cseg = idx & 7;
      int arow = m0 + row; if (arow >= cnt) arow = cnt - 1;
      gload16(&As[idx * 8], A + (size_t)arow * K + k0 + cseg * 8);
    }
    #pragma unroll
    for (int it = 0; it < 4; ++it) {
      int idx = it * 256 + tid;
      int row = idx >> 3, cseg = idx & 7;
      gload16(&Bs[idx * 8], Bw + (size_t)(n0 + row) * K + k0 + cseg * 8);
    }
    __syncthreads();   // drains vmcnt(0) before barrier

    bf16x8 av[4][2], bv[4][2];
    #pragma unroll
    for (int mf = 0; mf < 4; ++mf)
      #pragma unroll
      for (int kk = 0; kk < 2; ++kk)
        av[mf][kk] = *(const bf16x8*)&As[(wr * 64 + mf * 16 + fr) * BK + kk * 32 + fkb];
    #pragma unroll
    for (int nf = 0; nf < 4; ++nf)
      #pragma unroll
      for (int kk = 0; kk < 2; ++kk)
        bv[nf][kk] = *(const bf16x8*)&Bs[(wc * 64 + nf * 16 + fr) * BK + kk * 32 + fkb];

    #pragma unroll
    for (int kk = 0; kk < 2; ++kk)
      #pragma unroll
      for (int mf = 0; mf < 4; ++mf)
        #pragma unroll
        for (int nf = 0; nf < 4; ++nf)
          acc[mf][nf] = mfma16(av[mf][kk], bv[nf][kk], acc[mf][nf]);
    __syncthreads();
  }

  // epilogue: C/D layout col=lane&15, row=(lane>>4)*4+j
  #pragma unroll
  for (int mf = 0; mf < 4; ++mf) {
    const int rb = wr * 64 + mf * 16 + ((lane >> 4) << 2);
    #pragma unroll
    for (int nf = 0; nf < 4; ++nf) {
      const int col = n0 + wc * 64 + nf * 16 + fr;
      #pragma unroll
      for (int j = 0; j < 4; ++j) {
        const int lr = m0 + rb + j;
        if (lr < cnt) {
          float v = acc[mf][nf][j];
          if (EPI == 0) {
            Cact[(size_t)lr * HDIM + col] = f2bf(v + bias[col]);
          } else if (EPI == 1) {
            size_t idx = (size_t)lr * HDIM + col;
            float g = v + bias[col];
            float s = g / (1.f + expf(-g));
            Cact[idx] = f2bf(bf2f(Cact[idx]) * s);
          } else {
            const int grow = off + lr;
            const float gate = rowgate[grow];
            const int tok = rowtok[grow];
            Y[(size_t)tok * DDIM + col] += (v + bias[col]) * gate;
          }
        }
      }
    }
  }
}

__global__ void k_loss(const float* __restrict__ gwsum, float* __restrict__ out_loss) {
  if (threadIdx.x == 0) {
    float s = 0.f;
    for (int e = 0; e < NEXP; ++e) {
      float d = gwsum[e] / (float)T_TOK - 1.f / (float)NEXP;
      s += d * d;
    }
    out_loss[0] = (s / (float)NEXP) * 0.01f;
  }
}

extern "C" void kernel_launch(void* const* d_in, const int* in_sizes, int n_in,
                              void* d_out, int out_size, void* d_ws, size_t ws_size,
                              hipStream_t stream) {
  const float* x      = (const float*)d_in[0];
  const float* noise  = (const float*)d_in[1];
  const float* gate_w = (const float*)d_in[2];
  const float* nw     = (const float*)d_in[3];
  const float* w1     = (const float*)d_in[4];
  const float* b1     = (const float*)d_in[5];
  const float* w2     = (const float*)d_in[6];
  const float* b2     = (const float*)d_in[7];
  const float* wp     = (const float*)d_in[8];
  const float* bp     = (const float*)d_in[9];
  float* y = (float*)d_out;

  if (ws_size < WS_NEEDED) return;   // diagnostic: output stays zero

  char* ws = (char*)d_ws;
  int*   counts  = (int*)(ws + OFF_CNT);
  int*   offsets = (int*)(ws + OFF_OFFS);
  int*   cursors = (int*)(ws + OFF_CURS);
  float* gwsum   = (float*)(ws + OFF_GWSUM);
  int*   tope    = (int*)(ws + OFF_TOPE);
  float* topw    = (float*)(ws + OFF_TOPW);
  int*   rowtok  = (int*)(ws + OFF_ROWTOK);
  float* rowgate = (float*)(ws + OFF_ROWG);
  unsigned short* Xg  = (unsigned short*)(ws + OFF_XG);
  unsigned short* w1b = (unsigned short*)(ws + OFF_W1B);
  unsigned short* w2b = (unsigned short*)(ws + OFF_W2B);
  unsigned short* wpb = (unsigned short*)(ws + OFF_WPB);
  unsigned short* act = (unsigned short*)(ws + OFF_ACT);

  hipMemsetAsync(d_ws, 0, 256, stream);
  hipMemsetAsync(d_out, 0, (size_t)out_size * sizeof(float), stream);

  k_gate<<<T_TOK / 4, 256, 0, stream>>>(x, noise, gate_w, nw, counts, gwsum, tope, topw);
  k_scan<<<1, 64, 0, stream>>>(counts, offsets, cursors);
  k_scatter<<<T_TOK / 4, 256, 0, stream>>>(x, tope, topw, cursors, rowtok, rowgate, Xg);

  for (int e = 0; e < NEXP; ++e) {
    k_cast<<<3072, 256, 0, stream>>>(w1 + (size_t)e * HDIM * DDIM,
                                     w2 + (size_t)e * HDIM * DDIM,
                                     wp + (size_t)e * HDIM * DDIM,
                                     w1b, w2b, wpb, HDIM * DDIM);
    k_gemm<0><<<dim3(T_TOK / BM, HDIM / BN), 256, 0, stream>>>(
        Xg, w1b, DDIM, HDIM, counts, offsets, e, act, b1 + (size_t)e * HDIM,
        nullptr, nullptr, nullptr);
    k_gemm<1><<<dim3(T_TOK / BM, HDIM / BN), 256, 0, stream>>>(
        Xg, w2b, DDIM, HDIM, counts, offsets, e, act, b2 + (size_t)e * HDIM,
        nullptr, nullptr, nullptr);
    k_gemm<2><<<dim3(T_TOK / BM, DDIM / BN), 256, 0, stream>>>(
        act, wpb, HDIM, DDIM, counts, offsets, e, nullptr, bp + (size_t)e * DDIM,
        rowtok, rowgate, y);
  }
  k_loss<<<1, 64, 0, stream>>>(gwsum, y + (size_t)T_TOK * DDIM);
}

// Round 2
// 2924.207 us; speedup vs baseline: 1.1581x; 1.1581x over previous
//
#include <hip/hip_runtime.h>
#include <hip/hip_bf16.h>

#define T_TOK 16384
#define DDIM  1024
#define NEXP  8
#define HDIM  4096

#define BM 128
#define BN 128
#define BK 64

typedef __attribute__((ext_vector_type(8))) short bf16x8;
typedef __attribute__((ext_vector_type(4))) float f32x4;

__device__ __forceinline__ unsigned short f2bf(float f) {
  unsigned int x = __builtin_bit_cast(unsigned int, f);
  x += 0x7fffu + ((x >> 16) & 1u);   // RNE
  return (unsigned short)(x >> 16);
}
__device__ __forceinline__ float bf2f(unsigned short u) {
  unsigned int x = ((unsigned int)u) << 16;
  return __builtin_bit_cast(float, x);
}
__device__ __forceinline__ void gload16(void* lds, const void* g) {
  __builtin_amdgcn_global_load_lds(
      (const __attribute__((address_space(1))) unsigned int*)g,
      (__attribute__((address_space(3))) unsigned int*)lds, 16, 0, 0);
}
__device__ __forceinline__ f32x4 mfma16(bf16x8 a, bf16x8 b, f32x4 c) {
  return __builtin_amdgcn_mfma_f32_16x16x32_bf16(a, b, c, 0, 0, 0);
}

// ---------------- workspace layout (bytes) ----------------
#define OFF_GWSUM  ((size_t)0)                    // 8 float (needs zero)
#define OFF_CNT    ((size_t)64)                   // 8 int   (written by k_scan)
#define OFF_OFFS   ((size_t)128)                  // 8 int   (written by k_scan)
#define OFF_BLK    ((size_t)1024)                 // 64*8 int
#define OFF_GBASE  ((size_t)4096)                 // 64*8 int
#define OFF_TOPE   ((size_t)8192)                           // T*2 int
#define OFF_TOPW   (OFF_TOPE   + (size_t)T_TOK*2*4)         // T*2 float
#define OFF_LRANK  (OFF_TOPW   + (size_t)T_TOK*2*4)         // T uint
#define OFF_ROWTOK (OFF_LRANK  + (size_t)T_TOK*4)           // 2T int
#define OFF_ROWG   (OFF_ROWTOK + (size_t)T_TOK*2*4)         // 2T float
#define OFF_RFLAG  (OFF_ROWG   + (size_t)T_TOK*2*4)         // 2T int
#define OFF_XG     ((size_t)1 << 20)                        // 2T x D bf16
#define OFF_W1B    (OFF_XG  + (size_t)2*T_TOK*DDIM*2)
#define OFF_W2B    (OFF_W1B + (size_t)HDIM*DDIM*2)
#define OFF_WPB    (OFF_W2B + (size_t)HDIM*DDIM*2)
#define OFF_ACT    (OFF_WPB + (size_t)HDIM*DDIM*2)          // T x H bf16
#define WS_NEEDED  (OFF_ACT + (size_t)T_TOK*HDIM*2)

// ---------------- gating ----------------
__global__ __launch_bounds__(256) void k_gate(
    const float* __restrict__ x, const float* __restrict__ noise,
    const float* __restrict__ gate_w, const float* __restrict__ nw,
    float* __restrict__ gwsum, int* __restrict__ tope, float* __restrict__ topw)
{
  __shared__ float gw_s[NEXP * DDIM];     // 32 KB
  __shared__ float blk_gw[NEXP];
  const int tid = threadIdx.x;
  if (tid < NEXP) blk_gw[tid] = 0.f;
  {
    float4* dst = (float4*)gw_s;
    const float4* src = (const float4*)gate_w;
    for (int i = tid; i < NEXP * DDIM / 4; i += 256) dst[i] = src[i];
  }
  __syncthreads();

  const int wv = tid >> 6, lane = tid & 63;
  const int t = blockIdx.x * 4 + wv;

  const float4* xr = (const float4*)(x + (size_t)t * DDIM);
  float4 xv[4];
  #pragma unroll
  for (int c = 0; c < 4; ++c) xv[c] = xr[lane + 64 * c];

  float logit[NEXP];
  #pragma unroll
  for (int e = 0; e < NEXP; ++e) {
    float p = 0.f;
    const float4* g4 = (const float4*)(gw_s + e * DDIM);
    #pragma unroll
    for (int c = 0; c < 4; ++c) {
      float4 g = g4[lane + 64 * c];
      p += xv[c].x * g.x + xv[c].y * g.y + xv[c].z * g.z + xv[c].w * g.w;
    }
    #pragma unroll
    for (int off = 32; off >= 1; off >>= 1) p += __shfl_xor(p, off, 64);
    logit[e] = p;
  }

  if (lane == 0) {
    float m = logit[0];
    #pragma unroll
    for (int e = 1; e < NEXP; ++e) m = fmaxf(m, logit[e]);
    float sm[NEXP]; float s = 0.f;
    #pragma unroll
    for (int e = 0; e < NEXP; ++e) { sm[e] = expf(logit[e] - m); s += sm[e]; }
    float inv = 1.f / s;
    #pragma unroll
    for (int e = 0; e < NEXP; ++e) atomicAdd(&blk_gw[e], sm[e] * inv);

    float ln[NEXP];
    #pragma unroll
    for (int e = 0; e < NEXP; ++e) ln[e] = logit[e] + noise[(size_t)t * NEXP + e] * nw[e];
    int i1 = 0; float v1 = ln[0];
    #pragma unroll
    for (int e = 1; e < NEXP; ++e) if (ln[e] > v1) { v1 = ln[e]; i1 = e; }
    int i2 = -1; float v2 = -3.4e38f;
    #pragma unroll
    for (int e = 0; e < NEXP; ++e) if (e != i1 && ln[e] > v2) { v2 = ln[e]; i2 = e; }
    float b = expf(v2 - v1);
    float wsum = 1.f + b;
    tope[2 * t] = i1; tope[2 * t + 1] = i2;
    topw[2 * t] = 1.f / wsum; topw[2 * t + 1] = b / wsum;
  }
  __syncthreads();
  if (tid < NEXP) atomicAdd(&gwsum[tid], blk_gw[tid]);
}

// per-256-token-block histogram + local ranks (LDS atomics only)
__global__ __launch_bounds__(256) void k_hist(
    const int* __restrict__ tope, unsigned int* __restrict__ lrank,
    int* __restrict__ blkcnt)
{
  __shared__ int cnt8[NEXP];
  const int tid = threadIdx.x;
  const int t = blockIdx.x * 256 + tid;
  if (tid < NEXP) cnt8[tid] = 0;
  __syncthreads();
  const int e0 = tope[2 * t], e1 = tope[2 * t + 1];
  const int lr0 = atomicAdd(&cnt8[e0], 1);
  const int lr1 = atomicAdd(&cnt8[e1], 1);
  lrank[t] = (unsigned int)lr0 | ((unsigned int)lr1 << 16);
  __syncthreads();
  if (tid < NEXP) blkcnt[blockIdx.x * NEXP + tid] = cnt8[tid];
}

// single block: per-expert prefix over 64 hist blocks + expert offsets + loss
__global__ __launch_bounds__(512) void k_scan(
    const int* __restrict__ blkcnt, int* __restrict__ gbase,
    int* __restrict__ counts, int* __restrict__ offsets,
    const float* __restrict__ gwsum, float* __restrict__ out_loss)
{
  __shared__ int ld[64][NEXP];
  __shared__ int sc[64][NEXP];
  __shared__ int tot[NEXP];
  __shared__ int off8[NEXP];
  const int tid = threadIdx.x;
  const int b = tid >> 3, e = tid & 7;
  ld[b][e] = blkcnt[b * NEXP + e];
  __syncthreads();
  if (tid < NEXP) {
    int run = 0;
    for (int i = 0; i < 64; ++i) { sc[i][tid] = run; run += ld[i][tid]; }
    tot[tid] = run;
  }
  __syncthreads();
  if (tid == 0) {
    int o = 0;
    for (int i = 0; i < NEXP; ++i) {
      off8[i] = o; offsets[i] = o; counts[i] = tot[i]; o += tot[i];
    }
    float s = 0.f;
    for (int i = 0; i < NEXP; ++i) {
      float d = gwsum[i] / (float)T_TOK - 1.f / (float)NEXP;
      s += d * d;
    }
    out_loss[0] = (s / (float)NEXP) * 0.01f;
  }
  __syncthreads();
  gbase[b * NEXP + e] = off8[e] + sc[b][e];
}

// gather x -> bf16 rows at deterministic destinations; write row metadata
__global__ __launch_bounds__(256) void k_copy(
    const float* __restrict__ x, const int* __restrict__ tope,
    const float* __restrict__ topw, const unsigned int* __restrict__ lrank,
    const int* __restrict__ gbase,
    int* __restrict__ rowtok, float* __restrict__ rowgate,
    int* __restrict__ rowflag, unsigned short* __restrict__ Xg)
{
  const int tid = threadIdx.x;
  const int wv = tid >> 6, lane = tid & 63;
  const int t = blockIdx.x * 4 + wv;
  const int e0 = tope[2 * t], e1 = tope[2 * t + 1];
  const unsigned int lr = lrank[t];
  const int hb = t >> 8;
  const int r0 = gbase[hb * NEXP + e0] + (int)(lr & 0xffffu);
  const int r1 = gbase[hb * NEXP + e1] + (int)(lr >> 16);
  if (lane == 0) {
    rowtok[r0] = t; rowtok[r1] = t;
    rowgate[r0] = topw[2 * t]; rowgate[r1] = topw[2 * t + 1];
    rowflag[r0] = (e0 < e1) ? 1 : 0;
    rowflag[r1] = (e1 < e0) ? 1 : 0;
  }
  const float4* xr = (const float4*)(x + (size_t)t * DDIM);
  ushort4 o[4];
  #pragma unroll
  for (int c = 0; c < 4; ++c) {
    float4 v = xr[lane + 64 * c];
    o[c].x = f2bf(v.x); o[c].y = f2bf(v.y); o[c].z = f2bf(v.z); o[c].w = f2bf(v.w);
  }
  ushort4* d0 = (ushort4*)(Xg + (size_t)r0 * DDIM);
  ushort4* d1 = (ushort4*)(Xg + (size_t)r1 * DDIM);
  #pragma unroll
  for (int c = 0; c < 4; ++c) d0[lane + 64 * c] = o[c];
  #pragma unroll
  for (int c = 0; c < 4; ++c) d1[lane + 64 * c] = o[c];
}

// fp32 -> bf16 cast of one expert's three weight matrices
__global__ __launch_bounds__(256) void k_cast(
    const float* __restrict__ s1, const float* __restrict__ s2,
    const float* __restrict__ s3, unsigned short* __restrict__ d1,
    unsigned short* __restrict__ d2, unsigned short* __restrict__ d3, int n_each)
{
  const int n4 = n_each / 4;
  for (int i = blockIdx.x * blockDim.x + threadIdx.x; i < 3 * n4;
       i += gridDim.x * blockDim.x) {
    const float* s; unsigned short* d; int j = i;
    if (j < n4)            { s = s1; d = d1; }
    else if (j < 2 * n4)   { s = s2; d = d2; j -= n4; }
    else                   { s = s3; d = d3; j -= 2 * n4; }
    float4 v = ((const float4*)s)[j];
    ushort4 o;
    o.x = f2bf(v.x); o.y = f2bf(v.y); o.z = f2bf(v.z); o.w = f2bf(v.w);
    ((ushort4*)d)[j] = o;
  }
}

// ---------------- GEMM: C[m,n] = sum_k A[m,k]*B[n,k]  (both row-major)
// EPI 0: act[lr,n] = bf16(acc + b1[n])
// EPI 1: act[lr,n] = bf16( h * silu(acc + b2[n]) )   (h = previous act value)
// EPI 2: Y[tok,n] = / += gate * (acc + bp[n])  (store if first expert of token)
template<int EPI>
__global__ __launch_bounds__(256) void k_gemm(
    const unsigned short* __restrict__ Ab, const unsigned short* __restrict__ Bw,
    int K, int N,
    const int* __restrict__ counts, const int* __restrict__ offsets, int e,
    unsigned short* __restrict__ Cact, const float* __restrict__ bias,
    const int* __restrict__ rowtok, const float* __restrict__ rowgate,
    const int* __restrict__ rowflag, float* __restrict__ Y)
{
  const int cnt = counts[e];
  if (cnt <= 0) return;
  const int m0 = blockIdx.x * BM;
  if (m0 >= cnt) return;
  const int n0 = blockIdx.y * BN;
  const int off = offsets[e];
  const unsigned short* A = (EPI == 2) ? Ab : (Ab + (size_t)off * K);
  const bool full = (m0 + BM) <= cnt;

  __shared__ unsigned short As[BM * BK];  // 16 KB
  __shared__ unsigned short Bs[BN * BK];  // 16 KB

  const int tid = threadIdx.x;
  const int wid = tid >> 6, lane = tid & 63;
  const int wr = wid >> 1, wc = wid & 1;          // 2x2 waves of 64x64
  const int fr  = lane & 15;
  const int fkb = (lane >> 4) * 8;

  f32x4 acc[4][4] = {};

  const int nsteps = K / BK;
  for (int kt = 0; kt < nsteps; ++kt) {
    const int k0 = kt * BK;
    #pragma unroll
    for (int it = 0; it < 4; ++it) {
      int idx = it * 256 + tid;
      int row = idx >> 3, cseg = idx & 7;
      int arow = m0 + row;
      if (!full && arow >= cnt) arow = cnt - 1;
      gload16(&As[idx * 8], A + (size_t)arow * K + k0 + cseg * 8);
    }
    #pragma unroll
    for (int it = 0; it < 4; ++it) {
      int idx = it * 256 + tid;
      int row = idx >> 3, cseg = idx & 7;
      gload16(&Bs[idx * 8], Bw + (size_t)(n0 + row) * K + k0 + cseg * 8);
    }
    __syncthreads();

    bf16x8 av[4][2], bv[4][2];
    #pragma unroll
    for (int mf = 0; mf < 4; ++mf)
      #pragma unroll
      for (int kk = 0; kk < 2; ++kk)
        av[mf][kk] = *(const bf16x8*)&As[(wr * 64 + mf * 16 + fr) * BK + kk * 32 + fkb];
    #pragma unroll
    for (int nf = 0; nf < 4; ++nf)
      #pragma unroll
      for (int kk = 0; kk < 2; ++kk)
        bv[nf][kk] = *(const bf16x8*)&Bs[(wc * 64 + nf * 16 + fr) * BK + kk * 32 + fkb];

    #pragma unroll
    for (int kk = 0; kk < 2; ++kk)
      #pragma unroll
      for (int mf = 0; mf < 4; ++mf)
        #pragma unroll
        for (int nf = 0; nf < 4; ++nf)
          acc[mf][nf] = mfma16(av[mf][kk], bv[nf][kk], acc[mf][nf]);
    __syncthreads();
  }

  // epilogue: C/D layout col=lane&15, row=(lane>>4)*4+j
  #pragma unroll
  for (int mf = 0; mf < 4; ++mf) {
    const int rb = wr * 64 + mf * 16 + ((lane >> 4) << 2);
    #pragma unroll
    for (int nf = 0; nf < 4; ++nf) {
      const int col = n0 + wc * 64 + nf * 16 + fr;
      #pragma unroll
      for (int j = 0; j < 4; ++j) {
        const int lr = m0 + rb + j;
        if (full || lr < cnt) {
          float v = acc[mf][nf][j];
          if (EPI == 0) {
            Cact[(size_t)lr * HDIM + col] = f2bf(v + bias[col]);
          } else if (EPI == 1) {
            size_t idx = (size_t)lr * HDIM + col;
            float g = v + bias[col];
            float s = g / (1.f + expf(-g));
            Cact[idx] = f2bf(bf2f(Cact[idx]) * s);
          } else {
            const int grow = off + lr;
            const float gate = rowgate[grow];
            const int tok = rowtok[grow];
            float o = (v + bias[col]) * gate;
            float* yp = &Y[(size_t)tok * DDIM + col];
            if (rowflag[grow]) *yp = o; else *yp += o;
          }
        }
      }
    }
  }
}

extern "C" void kernel_launch(void* const* d_in, const int* in_sizes, int n_in,
                              void* d_out, int out_size, void* d_ws, size_t ws_size,
                              hipStream_t stream) {
  const float* x      = (const float*)d_in[0];
  const float* noise  = (const float*)d_in[1];
  const float* gate_w = (const float*)d_in[2];
  const float* nw     = (const float*)d_in[3];
  const float* w1     = (const float*)d_in[4];
  const float* b1     = (const float*)d_in[5];
  const float* w2     = (const float*)d_in[6];
  const float* b2     = (const float*)d_in[7];
  const float* wp     = (const float*)d_in[8];
  const float* bp     = (const float*)d_in[9];
  float* y = (float*)d_out;

  if (ws_size < WS_NEEDED) return;   // diagnostic: output stays poisoned

  char* ws = (char*)d_ws;
  float* gwsum   = (float*)(ws + OFF_GWSUM);
  int*   counts  = (int*)(ws + OFF_CNT);
  int*   offsets = (int*)(ws + OFF_OFFS);
  int*   blkcnt  = (int*)(ws + OFF_BLK);
  int*   gbase   = (int*)(ws + OFF_GBASE);
  int*   tope    = (int*)(ws + OFF_TOPE);
  float* topw    = (float*)(ws + OFF_TOPW);
  unsigned int* lrank = (unsigned int*)(ws + OFF_LRANK);
  int*   rowtok  = (int*)(ws + OFF_ROWTOK);
  float* rowgate = (float*)(ws + OFF_ROWG);
  int*   rowflag = (int*)(ws + OFF_RFLAG);
  unsigned short* Xg  = (unsigned short*)(ws + OFF_XG);
  unsigned short* w1b = (unsigned short*)(ws + OFF_W1B);
  unsigned short* w2b = (unsigned short*)(ws + OFF_W2B);
  unsigned short* wpb = (unsigned short*)(ws + OFF_WPB);
  unsigned short* act = (unsigned short*)(ws + OFF_ACT);

  hipMemsetAsync(d_ws, 0, 64, stream);   // gwsum only

  k_gate<<<T_TOK / 4, 256, 0, stream>>>(x, noise, gate_w, nw, gwsum, tope, topw);
  k_hist<<<T_TOK / 256, 256, 0, stream>>>(tope, lrank, blkcnt);
  k_scan<<<1, 512, 0, stream>>>(blkcnt, gbase, counts, offsets, gwsum,
                                y + (size_t)T_TOK * DDIM);
  k_copy<<<T_TOK / 4, 256, 0, stream>>>(x, tope, topw, lrank, gbase,
                                        rowtok, rowgate, rowflag, Xg);

  for (int e = 0; e < NEXP; ++e) {
    k_cast<<<3072, 256, 0, stream>>>(w1 + (size_t)e * HDIM * DDIM,
                                     w2 + (size_t)e * HDIM * DDIM,
                                     wp + (size_t)e * HDIM * DDIM,
                                     w1b, w2b, wpb, HDIM * DDIM);
    k_gemm<0><<<dim3(T_TOK / BM, HDIM / BN), 256, 0, stream>>>(
        Xg, w1b, DDIM, HDIM, counts, offsets, e, act, b1 + (size_t)e * HDIM,
        nullptr, nullptr, nullptr, nullptr);
    k_gemm<1><<<dim3(T_TOK / BM, HDIM / BN), 256, 0, stream>>>(
        Xg, w2b, DDIM, HDIM, counts, offsets, e, act, b2 + (size_t)e * HDIM,
        nullptr, nullptr, nullptr, nullptr);
    k_gemm<2><<<dim3(T_TOK / BM, DDIM / BN), 256, 0, stream>>>(
        act, wpb, HDIM, DDIM, counts, offsets, e, nullptr, bp + (size_t)e * DDIM,
        rowtok, rowgate, rowflag, y);
  }
}

// Round 3
// 2480.388 us; speedup vs baseline: 1.3654x; 1.1789x over previous
//
#include <hip/hip_runtime.h>
#include <hip/hip_bf16.h>

#define T_TOK 16384
#define DDIM  1024
#define NEXP  8
#define HDIM  4096

#define BM 128
#define BN 128
#define BK 64

typedef __attribute__((ext_vector_type(8))) short bf16x8;
typedef __attribute__((ext_vector_type(4))) float f32x4;

__device__ __forceinline__ unsigned short f2bf(float f) {
  unsigned int x = __builtin_bit_cast(unsigned int, f);
  x += 0x7fffu + ((x >> 16) & 1u);   // RNE
  return (unsigned short)(x >> 16);
}
__device__ __forceinline__ float bf2f(unsigned short u) {
  unsigned int x = ((unsigned int)u) << 16;
  return __builtin_bit_cast(float, x);
}
__device__ __forceinline__ void gload16(void* lds, const void* g) {
  __builtin_amdgcn_global_load_lds(
      (const __attribute__((address_space(1))) unsigned int*)g,
      (__attribute__((address_space(3))) unsigned int*)lds, 16, 0, 0);
}
__device__ __forceinline__ f32x4 mfma16(bf16x8 a, bf16x8 b, f32x4 c) {
  return __builtin_amdgcn_mfma_f32_16x16x32_bf16(a, b, c, 0, 0, 0);
}

// ---------------- workspace layout (bytes) ----------------
#define OFF_GWSUM  ((size_t)0)                    // 8 float (needs zero)
#define OFF_CNT    ((size_t)64)                   // 8 int
#define OFF_OFFS   ((size_t)128)                  // 8 int
#define OFF_BLK    ((size_t)1024)                 // 64*8 int
#define OFF_GBASE  ((size_t)4096)                 // 64*8 int
#define OFF_TOPE   ((size_t)8192)                           // T*2 int
#define OFF_TOPW   (OFF_TOPE   + (size_t)T_TOK*2*4)         // T*2 float
#define OFF_LRANK  (OFF_TOPW   + (size_t)T_TOK*2*4)         // T uint
#define OFF_ROWTOK (OFF_LRANK  + (size_t)T_TOK*4)           // 2T int
#define OFF_ROWG   (OFF_ROWTOK + (size_t)T_TOK*2*4)         // 2T float
#define OFF_RFLAG  (OFF_ROWG   + (size_t)T_TOK*2*4)         // 2T int
#define OFF_XG     ((size_t)1 << 20)                        // 2T x D bf16
#define OFF_W1B    (OFF_XG  + (size_t)2*T_TOK*DDIM*2)
#define OFF_W2B    (OFF_W1B + (size_t)HDIM*DDIM*2)
#define OFF_WPB    (OFF_W2B + (size_t)HDIM*DDIM*2)
#define OFF_ACT    (OFF_WPB + (size_t)HDIM*DDIM*2)          // T x H bf16
#define WS_NEEDED  (OFF_ACT + (size_t)T_TOK*HDIM*2)

// ---------------- gating ----------------
__global__ __launch_bounds__(256) void k_gate(
    const float* __restrict__ x, const float* __restrict__ noise,
    const float* __restrict__ gate_w, const float* __restrict__ nw,
    float* __restrict__ gwsum, int* __restrict__ tope, float* __restrict__ topw)
{
  __shared__ float gw_s[NEXP * DDIM];     // 32 KB
  __shared__ float blk_gw[NEXP];
  const int tid = threadIdx.x;
  if (tid < NEXP) blk_gw[tid] = 0.f;
  {
    float4* dst = (float4*)gw_s;
    const float4* src = (const float4*)gate_w;
    for (int i = tid; i < NEXP * DDIM / 4; i += 256) dst[i] = src[i];
  }
  __syncthreads();

  const int wv = tid >> 6, lane = tid & 63;
  const int t = blockIdx.x * 4 + wv;

  const float4* xr = (const float4*)(x + (size_t)t * DDIM);
  float4 xv[4];
  #pragma unroll
  for (int c = 0; c < 4; ++c) xv[c] = xr[lane + 64 * c];

  float logit[NEXP];
  #pragma unroll
  for (int e = 0; e < NEXP; ++e) {
    float p = 0.f;
    const float4* g4 = (const float4*)(gw_s + e * DDIM);
    #pragma unroll
    for (int c = 0; c < 4; ++c) {
      float4 g = g4[lane + 64 * c];
      p += xv[c].x * g.x + xv[c].y * g.y + xv[c].z * g.z + xv[c].w * g.w;
    }
    #pragma unroll
    for (int off = 32; off >= 1; off >>= 1) p += __shfl_xor(p, off, 64);
    logit[e] = p;
  }

  if (lane == 0) {
    float m = logit[0];
    #pragma unroll
    for (int e = 1; e < NEXP; ++e) m = fmaxf(m, logit[e]);
    float sm[NEXP]; float s = 0.f;
    #pragma unroll
    for (int e = 0; e < NEXP; ++e) { sm[e] = expf(logit[e] - m); s += sm[e]; }
    float inv = 1.f / s;
    #pragma unroll
    for (int e = 0; e < NEXP; ++e) atomicAdd(&blk_gw[e], sm[e] * inv);

    float ln[NEXP];
    #pragma unroll
    for (int e = 0; e < NEXP; ++e) ln[e] = logit[e] + noise[(size_t)t * NEXP + e] * nw[e];
    int i1 = 0; float v1 = ln[0];
    #pragma unroll
    for (int e = 1; e < NEXP; ++e) if (ln[e] > v1) { v1 = ln[e]; i1 = e; }
    int i2 = -1; float v2 = -3.4e38f;
    #pragma unroll
    for (int e = 0; e < NEXP; ++e) if (e != i1 && ln[e] > v2) { v2 = ln[e]; i2 = e; }
    float b = expf(v2 - v1);
    float wsum = 1.f + b;
    tope[2 * t] = i1; tope[2 * t + 1] = i2;
    topw[2 * t] = 1.f / wsum; topw[2 * t + 1] = b / wsum;
  }
  __syncthreads();
  if (tid < NEXP) atomicAdd(&gwsum[tid], blk_gw[tid]);
}

// per-256-token-block histogram + local ranks (LDS atomics only)
__global__ __launch_bounds__(256) void k_hist(
    const int* __restrict__ tope, unsigned int* __restrict__ lrank,
    int* __restrict__ blkcnt)
{
  __shared__ int cnt8[NEXP];
  const int tid = threadIdx.x;
  const int t = blockIdx.x * 256 + tid;
  if (tid < NEXP) cnt8[tid] = 0;
  __syncthreads();
  const int e0 = tope[2 * t], e1 = tope[2 * t + 1];
  const int lr0 = atomicAdd(&cnt8[e0], 1);
  const int lr1 = atomicAdd(&cnt8[e1], 1);
  lrank[t] = (unsigned int)lr0 | ((unsigned int)lr1 << 16);
  __syncthreads();
  if (tid < NEXP) blkcnt[blockIdx.x * NEXP + tid] = cnt8[tid];
}

// single block: per-expert prefix over 64 hist blocks + expert offsets + loss
__global__ __launch_bounds__(512) void k_scan(
    const int* __restrict__ blkcnt, int* __restrict__ gbase,
    int* __restrict__ counts, int* __restrict__ offsets,
    const float* __restrict__ gwsum, float* __restrict__ out_loss)
{
  __shared__ int ld[64][NEXP];
  __shared__ int sc[64][NEXP];
  __shared__ int tot[NEXP];
  __shared__ int off8[NEXP];
  const int tid = threadIdx.x;
  const int b = tid >> 3, e = tid & 7;
  ld[b][e] = blkcnt[b * NEXP + e];
  __syncthreads();
  if (tid < NEXP) {
    int run = 0;
    for (int i = 0; i < 64; ++i) { sc[i][tid] = run; run += ld[i][tid]; }
    tot[tid] = run;
  }
  __syncthreads();
  if (tid == 0) {
    int o = 0;
    for (int i = 0; i < NEXP; ++i) {
      off8[i] = o; offsets[i] = o; counts[i] = tot[i]; o += tot[i];
    }
    float s = 0.f;
    for (int i = 0; i < NEXP; ++i) {
      float d = gwsum[i] / (float)T_TOK - 1.f / (float)NEXP;
      s += d * d;
    }
    out_loss[0] = (s / (float)NEXP) * 0.01f;
  }
  __syncthreads();
  gbase[b * NEXP + e] = off8[e] + sc[b][e];
}

// gather x -> bf16 rows at deterministic destinations; write row metadata
__global__ __launch_bounds__(256) void k_copy(
    const float* __restrict__ x, const int* __restrict__ tope,
    const float* __restrict__ topw, const unsigned int* __restrict__ lrank,
    const int* __restrict__ gbase,
    int* __restrict__ rowtok, float* __restrict__ rowgate,
    int* __restrict__ rowflag, unsigned short* __restrict__ Xg)
{
  const int tid = threadIdx.x;
  const int wv = tid >> 6, lane = tid & 63;
  const int t = blockIdx.x * 4 + wv;
  const int e0 = tope[2 * t], e1 = tope[2 * t + 1];
  const unsigned int lr = lrank[t];
  const int hb = t >> 8;
  const int r0 = gbase[hb * NEXP + e0] + (int)(lr & 0xffffu);
  const int r1 = gbase[hb * NEXP + e1] + (int)(lr >> 16);
  if (lane == 0) {
    rowtok[r0] = t; rowtok[r1] = t;
    rowgate[r0] = topw[2 * t]; rowgate[r1] = topw[2 * t + 1];
    rowflag[r0] = (e0 < e1) ? 1 : 0;
    rowflag[r1] = (e1 < e0) ? 1 : 0;
  }
  const float4* xr = (const float4*)(x + (size_t)t * DDIM);
  ushort4 o[4];
  #pragma unroll
  for (int c = 0; c < 4; ++c) {
    float4 v = xr[lane + 64 * c];
    o[c].x = f2bf(v.x); o[c].y = f2bf(v.y); o[c].z = f2bf(v.z); o[c].w = f2bf(v.w);
  }
  ushort4* d0 = (ushort4*)(Xg + (size_t)r0 * DDIM);
  ushort4* d1 = (ushort4*)(Xg + (size_t)r1 * DDIM);
  #pragma unroll
  for (int c = 0; c < 4; ++c) d0[lane + 64 * c] = o[c];
  #pragma unroll
  for (int c = 0; c < 4; ++c) d1[lane + 64 * c] = o[c];
}

// fp32 -> bf16 cast of one expert's three weight matrices
__global__ __launch_bounds__(256) void k_cast(
    const float* __restrict__ s1, const float* __restrict__ s2,
    const float* __restrict__ s3, unsigned short* __restrict__ d1,
    unsigned short* __restrict__ d2, unsigned short* __restrict__ d3, int n_each)
{
  const int n4 = n_each / 4;
  for (int i = blockIdx.x * blockDim.x + threadIdx.x; i < 3 * n4;
       i += gridDim.x * blockDim.x) {
    const float* s; unsigned short* d; int j = i;
    if (j < n4)            { s = s1; d = d1; }
    else if (j < 2 * n4)   { s = s2; d = d2; j -= n4; }
    else                   { s = s3; d = d3; j -= 2 * n4; }
    float4 v = ((const float4*)s)[j];
    ushort4 o;
    o.x = f2bf(v.x); o.y = f2bf(v.y); o.z = f2bf(v.z); o.w = f2bf(v.w);
    ((ushort4*)d)[j] = o;
  }
}

// ---------------- GEMM: C[m,n] = sum_k A[m,k]*B[n,k]  (both row-major)
// T3-min prefetch pipeline (double-buffered LDS) + XOR bank swizzle
// (linear gload_lds dest + inverse-permuted global source + XOR'd ds_read).
// EPI 0: act[lr,n] = bf16(acc + b1[n])
// EPI 1: act[lr,n] = bf16( h * silu(acc + b2[n]) )
// EPI 2: Y[tok,n] = / += gate * (acc + bp[n])
template<int EPI>
__global__ __launch_bounds__(256) void k_gemm(
    const unsigned short* __restrict__ Ab, const unsigned short* __restrict__ Bw,
    int K, int N,
    const int* __restrict__ counts, const int* __restrict__ offsets, int e,
    unsigned short* __restrict__ Cact, const float* __restrict__ bias,
    const int* __restrict__ rowtok, const float* __restrict__ rowgate,
    const int* __restrict__ rowflag, float* __restrict__ Y)
{
  const int cnt = counts[e];
  if (cnt <= 0) return;
  const int m0 = blockIdx.x * BM;
  if (m0 >= cnt) return;
  const int n0 = blockIdx.y * BN;
  const int off = offsets[e];
  const unsigned short* A = (EPI == 2) ? Ab : (Ab + (size_t)off * K);
  const bool full = (m0 + BM) <= cnt;

  __shared__ unsigned short As[2][BM * BK];  // 2 x 16 KB
  __shared__ unsigned short Bs[2][BN * BK];  // 2 x 16 KB

  const int tid = threadIdx.x;
  const int wid = tid >> 6, lane = tid & 63;
  const int wr = wid >> 1, wc = wid & 1;          // 2x2 waves of 64x64
  const int fr = lane & 15;
  const int fq = lane >> 4;                       // 0..3

  // staging: idx -> (row = idx>>3, seg = idx&7); LDS dest linear (lane-ordered),
  // global source k-offset permuted by seg ^ (row&7)  [rule #21 involution]
  auto stage = [&](int kt, int cur) {
    const int k0 = kt * BK;
    #pragma unroll
    for (int it = 0; it < 4; ++it) {
      const int idx = it * 256 + tid;
      const int row = idx >> 3, seg = idx & 7;
      const int koff = ((seg ^ (row & 7)) << 3);
      int arow = m0 + row;
      if (!full && arow >= cnt) arow = cnt - 1;
      gload16(&As[cur][idx * 8], A + (size_t)arow * K + k0 + koff);
    }
    #pragma unroll
    for (int it = 0; it < 4; ++it) {
      const int idx = it * 256 + tid;
      const int row = idx >> 3, seg = idx & 7;
      const int koff = ((seg ^ (row & 7)) << 3);
      gload16(&Bs[cur][idx * 8], Bw + (size_t)(n0 + row) * K + k0 + koff);
    }
  };

  f32x4 acc[4][4] = {};
  const int nsteps = K / BK;

  stage(0, 0);
  __syncthreads();              // drains vmcnt(0): buf0 ready
  int cur = 0;

  for (int kt = 0; kt < nsteps; ++kt) {
    const bool has_next = (kt + 1 < nsteps);
    if (has_next) stage(kt + 1, cur ^ 1);   // prefetch in flight under compute

    bf16x8 av[4][2], bv[4][2];
    #pragma unroll
    for (int mf = 0; mf < 4; ++mf) {
      const int row = wr * 64 + mf * 16 + fr;
      #pragma unroll
      for (int kk = 0; kk < 2; ++kk) {
        const int seg = (kk * 4 + fq) ^ (row & 7);
        av[mf][kk] = *(const bf16x8*)&As[cur][row * BK + seg * 8];
      }
    }
    #pragma unroll
    for (int nf = 0; nf < 4; ++nf) {
      const int row = wc * 64 + nf * 16 + fr;
      #pragma unroll
      for (int kk = 0; kk < 2; ++kk) {
        const int seg = (kk * 4 + fq) ^ (row & 7);
        bv[nf][kk] = *(const bf16x8*)&Bs[cur][row * BK + seg * 8];
      }
    }

    #pragma unroll
    for (int kk = 0; kk < 2; ++kk)
      #pragma unroll
      for (int mf = 0; mf < 4; ++mf)
        #pragma unroll
        for (int nf = 0; nf < 4; ++nf)
          acc[mf][nf] = mfma16(av[mf][kk], bv[nf][kk], acc[mf][nf]);

    if (has_next) {
      __syncthreads();          // vmcnt(0)+lgkmcnt(0)+barrier: next buf ready
      cur ^= 1;
    }
  }

  // epilogue: C/D layout col=lane&15, row=(lane>>4)*4+j
  #pragma unroll
  for (int mf = 0; mf < 4; ++mf) {
    const int rb = wr * 64 + mf * 16 + (fq << 2);
    #pragma unroll
    for (int nf = 0; nf < 4; ++nf) {
      const int col = n0 + wc * 64 + nf * 16 + fr;
      #pragma unroll
      for (int j = 0; j < 4; ++j) {
        const int lr = m0 + rb + j;
        if (full || lr < cnt) {
          float v = acc[mf][nf][j];
          if (EPI == 0) {
            Cact[(size_t)lr * HDIM + col] = f2bf(v + bias[col]);
          } else if (EPI == 1) {
            size_t idx = (size_t)lr * HDIM + col;
            float g = v + bias[col];
            float s = g / (1.f + expf(-g));
            Cact[idx] = f2bf(bf2f(Cact[idx]) * s);
          } else {
            const int grow = off + lr;
            const float gate = rowgate[grow];
            const int tok = rowtok[grow];
            float o = (v + bias[col]) * gate;
            float* yp = &Y[(size_t)tok * DDIM + col];
            if (rowflag[grow]) *yp = o; else *yp += o;
          }
        }
      }
    }
  }
}

extern "C" void kernel_launch(void* const* d_in, const int* in_sizes, int n_in,
                              void* d_out, int out_size, void* d_ws, size_t ws_size,
                              hipStream_t stream) {
  const float* x      = (const float*)d_in[0];
  const float* noise  = (const float*)d_in[1];
  const float* gate_w = (const float*)d_in[2];
  const float* nw     = (const float*)d_in[3];
  const float* w1     = (const float*)d_in[4];
  const float* b1     = (const float*)d_in[5];
  const float* w2     = (const float*)d_in[6];
  const float* b2     = (const float*)d_in[7];
  const float* wp     = (const float*)d_in[8];
  const float* bp     = (const float*)d_in[9];
  float* y = (float*)d_out;

  if (ws_size < WS_NEEDED) return;   // diagnostic: output stays poisoned

  char* ws = (char*)d_ws;
  float* gwsum   = (float*)(ws + OFF_GWSUM);
  int*   counts  = (int*)(ws + OFF_CNT);
  int*   offsets = (int*)(ws + OFF_OFFS);
  int*   blkcnt  = (int*)(ws + OFF_BLK);
  int*   gbase   = (int*)(ws + OFF_GBASE);
  int*   tope    = (int*)(ws + OFF_TOPE);
  float* topw    = (float*)(ws + OFF_TOPW);
  unsigned int* lrank = (unsigned int*)(ws + OFF_LRANK);
  int*   rowtok  = (int*)(ws + OFF_ROWTOK);
  float* rowgate = (float*)(ws + OFF_ROWG);
  int*   rowflag = (int*)(ws + OFF_RFLAG);
  unsigned short* Xg  = (unsigned short*)(ws + OFF_XG);
  unsigned short* w1b = (unsigned short*)(ws + OFF_W1B);
  unsigned short* w2b = (unsigned short*)(ws + OFF_W2B);
  unsigned short* wpb = (unsigned short*)(ws + OFF_WPB);
  unsigned short* act = (unsigned short*)(ws + OFF_ACT);

  hipMemsetAsync(d_ws, 0, 64, stream);   // gwsum only

  k_gate<<<T_TOK / 4, 256, 0, stream>>>(x, noise, gate_w, nw, gwsum, tope, topw);
  k_hist<<<T_TOK / 256, 256, 0, stream>>>(tope, lrank, blkcnt);
  k_scan<<<1, 512, 0, stream>>>(blkcnt, gbase, counts, offsets, gwsum,
                                y + (size_t)T_TOK * DDIM);
  k_copy<<<T_TOK / 4, 256, 0, stream>>>(x, tope, topw, lrank, gbase,
                                        rowtok, rowgate, rowflag, Xg);

  for (int e = 0; e < NEXP; ++e) {
    k_cast<<<3072, 256, 0, stream>>>(w1 + (size_t)e * HDIM * DDIM,
                                     w2 + (size_t)e * HDIM * DDIM,
                                     wp + (size_t)e * HDIM * DDIM,
                                     w1b, w2b, wpb, HDIM * DDIM);
    k_gemm<0><<<dim3(T_TOK / BM, HDIM / BN), 256, 0, stream>>>(
        Xg, w1b, DDIM, HDIM, counts, offsets, e, act, b1 + (size_t)e * HDIM,
        nullptr, nullptr, nullptr, nullptr);
    k_gemm<1><<<dim3(T_TOK / BM, HDIM / BN), 256, 0, stream>>>(
        Xg, w2b, DDIM, HDIM, counts, offsets, e, act, b2 + (size_t)e * HDIM,
        nullptr, nullptr, nullptr, nullptr);
    k_gemm<2><<<dim3(T_TOK / BM, DDIM / BN), 256, 0, stream>>>(
        act, wpb, HDIM, DDIM, counts, offsets, e, nullptr, bp + (size_t)e * DDIM,
        rowtok, rowgate, rowflag, y);
  }
}

// Round 4
// 1694.242 us; speedup vs baseline: 1.9989x; 1.4640x over previous
//
#include <hip/hip_runtime.h>
#include <hip/hip_bf16.h>

#define T_TOK 16384
#define DDIM  1024
#define NEXP  8
#define HDIM  4096
#define HQ    1024            // H quarter
#define NQ    4

#define BM 128
#define BN 64
#define BK 64

typedef __attribute__((ext_vector_type(8))) short bf16x8;
typedef __attribute__((ext_vector_type(4))) float f32x4;

__device__ __forceinline__ unsigned short f2bf(float f) {
  unsigned int x = __builtin_bit_cast(unsigned int, f);
  x += 0x7fffu + ((x >> 16) & 1u);   // RNE
  return (unsigned short)(x >> 16);
}
__device__ __forceinline__ void gload16(void* lds, const void* g) {
  __builtin_amdgcn_global_load_lds(
      (const __attribute__((address_space(1))) unsigned int*)g,
      (__attribute__((address_space(3))) unsigned int*)lds, 16, 0, 0);
}
__device__ __forceinline__ f32x4 mfma16(bf16x8 a, bf16x8 b, f32x4 c) {
  return __builtin_amdgcn_mfma_f32_16x16x32_bf16(a, b, c, 0, 0, 0);
}

// ---------------- workspace layout (bytes) ----------------
#define OFF_GWSUM  ((size_t)0)           // 8 float (memset)
#define OFF_OFF16  ((size_t)64)          // 16 int
#define OFF_NP     ((size_t)128)         // 2 int: npP, npS
#define OFF_BLK    ((size_t)1024)        // 64*16 int
#define OFF_GBASE  ((size_t)8192)        // 64*16 int
#define OFF_PEXPP  ((size_t)16384)       // 160 int each
#define OFF_PM0P   ((size_t)17408)
#define OFF_PENDP  ((size_t)18432)
#define OFF_PEXPS  ((size_t)19456)
#define OFF_PM0S   ((size_t)20480)
#define OFF_PENDS  ((size_t)21504)
#define OFF_TOPE   ((size_t)32768)                          // T*2 int
#define OFF_TOPW   (OFF_TOPE   + (size_t)T_TOK*2*4)         // T*2 float
#define OFF_LRANK  (OFF_TOPW   + (size_t)T_TOK*2*4)         // T uint
#define OFF_ROWTOK (OFF_LRANK  + (size_t)T_TOK*4)           // 2T int
#define OFF_ROWG   (OFF_ROWTOK + (size_t)T_TOK*2*4)         // 2T float
#define OFF_XG     ((size_t)1 << 20)                        // 2T x D bf16 (64MiB)
#define OFF_ACTQ   (OFF_XG   + (size_t)2*T_TOK*DDIM*2)      // 2T x HQ bf16 (64MiB)
#define OFF_W1Q    (OFF_ACTQ + (size_t)2*T_TOK*HQ*2)        // E*HQ*D bf16 (16MiB)
#define OFF_W2Q    (OFF_W1Q  + (size_t)NEXP*HQ*DDIM*2)
#define OFF_WPQ    (OFF_W2Q  + (size_t)NEXP*HQ*DDIM*2)      // E*D*HQ bf16 (16MiB)
#define WS_NEEDED  (OFF_WPQ  + (size_t)NEXP*DDIM*HQ*2 + ((size_t)1<<20))

// ---------------- gating ----------------
__global__ __launch_bounds__(256) void k_gate(
    const float* __restrict__ x, const float* __restrict__ noise,
    const float* __restrict__ gate_w, const float* __restrict__ nw,
    float* __restrict__ gwsum, int* __restrict__ tope, float* __restrict__ topw)
{
  __shared__ float gw_s[NEXP * DDIM];
  __shared__ float blk_gw[NEXP];
  const int tid = threadIdx.x;
  if (tid < NEXP) blk_gw[tid] = 0.f;
  {
    float4* dst = (float4*)gw_s;
    const float4* src = (const float4*)gate_w;
    for (int i = tid; i < NEXP * DDIM / 4; i += 256) dst[i] = src[i];
  }
  __syncthreads();

  const int wv = tid >> 6, lane = tid & 63;
  const int t = blockIdx.x * 4 + wv;

  const float4* xr = (const float4*)(x + (size_t)t * DDIM);
  float4 xv[4];
  #pragma unroll
  for (int c = 0; c < 4; ++c) xv[c] = xr[lane + 64 * c];

  float logit[NEXP];
  #pragma unroll
  for (int e = 0; e < NEXP; ++e) {
    float p = 0.f;
    const float4* g4 = (const float4*)(gw_s + e * DDIM);
    #pragma unroll
    for (int c = 0; c < 4; ++c) {
      float4 g = g4[lane + 64 * c];
      p += xv[c].x * g.x + xv[c].y * g.y + xv[c].z * g.z + xv[c].w * g.w;
    }
    #pragma unroll
    for (int off = 32; off >= 1; off >>= 1) p += __shfl_xor(p, off, 64);
    logit[e] = p;
  }

  if (lane == 0) {
    float m = logit[0];
    #pragma unroll
    for (int e = 1; e < NEXP; ++e) m = fmaxf(m, logit[e]);
    float sm[NEXP]; float s = 0.f;
    #pragma unroll
    for (int e = 0; e < NEXP; ++e) { sm[e] = expf(logit[e] - m); s += sm[e]; }
    float inv = 1.f / s;
    #pragma unroll
    for (int e = 0; e < NEXP; ++e) atomicAdd(&blk_gw[e], sm[e] * inv);

    float ln[NEXP];
    #pragma unroll
    for (int e = 0; e < NEXP; ++e) ln[e] = logit[e] + noise[(size_t)t * NEXP + e] * nw[e];
    int i1 = 0; float v1 = ln[0];
    #pragma unroll
    for (int e = 1; e < NEXP; ++e) if (ln[e] > v1) { v1 = ln[e]; i1 = e; }
    int i2 = -1; float v2 = -3.4e38f;
    #pragma unroll
    for (int e = 0; e < NEXP; ++e) if (e != i1 && ln[e] > v2) { v2 = ln[e]; i2 = e; }
    float b = expf(v2 - v1);
    float wsum = 1.f + b;
    tope[2 * t] = i1; tope[2 * t + 1] = i2;
    topw[2 * t] = 1.f / wsum; topw[2 * t + 1] = b / wsum;
  }
  __syncthreads();
  if (tid < NEXP) atomicAdd(&gwsum[tid], blk_gw[tid]);
}

// per-256-token-block histogram over 16 (expert,region) bins
__global__ __launch_bounds__(256) void k_hist(
    const int* __restrict__ tope, unsigned int* __restrict__ lrank,
    int* __restrict__ blkcnt)
{
  __shared__ int cnt16[16];
  const int tid = threadIdx.x;
  const int t = blockIdx.x * 256 + tid;
  if (tid < 16) cnt16[tid] = 0;
  __syncthreads();
  const int e0 = tope[2 * t], e1 = tope[2 * t + 1];
  const int b0 = 2 * e0 + (e0 < e1 ? 0 : 1);
  const int b1 = 2 * e1 + (e1 < e0 ? 0 : 1);
  const int lr0 = atomicAdd(&cnt16[b0], 1);
  const int lr1 = atomicAdd(&cnt16[b1], 1);
  lrank[t] = (unsigned int)lr0 | ((unsigned int)lr1 << 16);
  __syncthreads();
  if (tid < 16) blkcnt[blockIdx.x * 16 + tid] = cnt16[tid];
}

// single block: prefix over 64 hist blocks x 16 bins, panel tables, loss
__global__ __launch_bounds__(512) void k_scan(
    const int* __restrict__ blkcnt, int* __restrict__ gbase,
    int* __restrict__ off16, int* __restrict__ np,
    int* __restrict__ pexpP, int* __restrict__ pm0P, int* __restrict__ pendP,
    int* __restrict__ pexpS, int* __restrict__ pm0S, int* __restrict__ pendS,
    const float* __restrict__ gwsum, float* __restrict__ out_loss)
{
  __shared__ int ld[64][16];
  __shared__ int sc[64][16];
  __shared__ int tot[16];
  __shared__ int o16[16];
  const int tid = threadIdx.x;
  for (int i = tid; i < 1024; i += 512) ld[i >> 4][i & 15] = blkcnt[i];
  __syncthreads();
  if (tid < 16) {
    int run = 0;
    for (int i = 0; i < 64; ++i) { sc[i][tid] = run; run += ld[i][tid]; }
    tot[tid] = run;
  }
  __syncthreads();
  if (tid == 0) {
    int o = 0;
    for (int b = 0; b < 16; ++b) { o16[b] = o; off16[b] = o; o += tot[b]; }
    int nP = 0, nS = 0;
    for (int b = 0; b < 16; ++b) {
      const int e = b >> 1, s = b & 1;
      const int beg = o16[b], end = beg + tot[b];
      for (int m = beg; m < end; m += BM) {
        const int me = (m + BM < end) ? (m + BM) : end;
        if (!s) { pexpP[nP] = e; pm0P[nP] = m; pendP[nP] = me; ++nP; }
        else    { pexpS[nS] = e; pm0S[nS] = m; pendS[nS] = me; ++nS; }
      }
    }
    np[0] = nP; np[1] = nS;
    float s = 0.f;
    for (int i = 0; i < NEXP; ++i) {
      float d = gwsum[i] / (float)T_TOK - 1.f / (float)NEXP;
      s += d * d;
    }
    out_loss[0] = (s / (float)NEXP) * 0.01f;
  }
  __syncthreads();
  for (int i = tid; i < 1024; i += 512)
    gbase[i] = o16[i & 15] + sc[i >> 4][i & 15];
}

// gather x -> bf16 rows at deterministic destinations; write row metadata
__global__ __launch_bounds__(256) void k_copy(
    const float* __restrict__ x, const int* __restrict__ tope,
    const float* __restrict__ topw, const unsigned int* __restrict__ lrank,
    const int* __restrict__ gbase,
    int* __restrict__ rowtok, float* __restrict__ rowgate,
    unsigned short* __restrict__ Xg)
{
  const int tid = threadIdx.x;
  const int wv = tid >> 6, lane = tid & 63;
  const int t = blockIdx.x * 4 + wv;
  const int e0 = tope[2 * t], e1 = tope[2 * t + 1];
  const int b0 = 2 * e0 + (e0 < e1 ? 0 : 1);
  const int b1 = 2 * e1 + (e1 < e0 ? 0 : 1);
  const unsigned int lr = lrank[t];
  const int hb = t >> 8;
  const int r0 = gbase[hb * 16 + b0] + (int)(lr & 0xffffu);
  const int r1 = gbase[hb * 16 + b1] + (int)(lr >> 16);
  if (lane == 0) {
    rowtok[r0] = t; rowtok[r1] = t;
    rowgate[r0] = topw[2 * t]; rowgate[r1] = topw[2 * t + 1];
  }
  const float4* xr = (const float4*)(x + (size_t)t * DDIM);
  ushort4 o[4];
  #pragma unroll
  for (int c = 0; c < 4; ++c) {
    float4 v = xr[lane + 64 * c];
    o[c].x = f2bf(v.x); o[c].y = f2bf(v.y); o[c].z = f2bf(v.z); o[c].w = f2bf(v.w);
  }
  ushort4* d0 = (ushort4*)(Xg + (size_t)r0 * DDIM);
  ushort4* d1 = (ushort4*)(Xg + (size_t)r1 * DDIM);
  #pragma unroll
  for (int c = 0; c < 4; ++c) d0[lane + 64 * c] = o[c];
  #pragma unroll
  for (int c = 0; c < 4; ++c) d1[lane + 64 * c] = o[c];
}

// cast quarter q of w1,w2: [E][HQ rows][D] fp32 -> bf16
__global__ __launch_bounds__(256) void k_castup(
    const float* __restrict__ w1, const float* __restrict__ w2,
    unsigned short* __restrict__ w1q, unsigned short* __restrict__ w2q, int q)
{
  const int N4 = NEXP * HQ * DDIM / 4;   // 2M float4 per mat
  for (int i = blockIdx.x * 256 + threadIdx.x; i < 2 * N4; i += gridDim.x * 256) {
    const float* s; unsigned short* d; int j = i;
    if (j < N4) { s = w1; d = w1q; } else { s = w2; d = w2q; j -= N4; }
    const int c4 = j & 255;              // 256 float4 per row
    const int rr = j >> 8;               // e*1024 + r
    const int e = rr >> 10, r = rr & 1023;
    float4 v = ((const float4*)s)[((size_t)e * HDIM + q * HQ + r) * 256 + c4];
    ushort4 o;
    o.x = f2bf(v.x); o.y = f2bf(v.y); o.z = f2bf(v.z); o.w = f2bf(v.w);
    ((ushort4*)d)[(size_t)rr * 256 + c4] = o;
  }
}

// cast quarter q of wp: [E][D rows][HQ cols] fp32 -> bf16 (cols q*HQ..)
__global__ __launch_bounds__(256) void k_castdn(
    const float* __restrict__ wp, unsigned short* __restrict__ wpq, int q)
{
  const int N4 = NEXP * DDIM * HQ / 4;   // 2M float4
  for (int i = blockIdx.x * 256 + threadIdx.x; i < N4; i += gridDim.x * 256) {
    const int c4 = i & 255;              // 256 float4 per row-quarter
    const int rr = i >> 8;               // e*1024 + d
    float4 v = ((const float4*)wp)[(size_t)rr * 1024 + q * 256 + c4];
    ushort4 o;
    o.x = f2bf(v.x); o.y = f2bf(v.y); o.z = f2bf(v.z); o.w = f2bf(v.w);
    ((ushort4*)wpq)[(size_t)rr * 256 + c4] = o;
  }
}

// ---------------- fused up+gate GEMM (grouped over all panels) ----------------
// act[r, cq] = (A@W1 + b1) * silu(A@W2 + b2), A = Xg rows, K = D = 1024
#define FGX 280
#define FGY 16
__global__ __launch_bounds__(256, 2) void k_fused(
    const unsigned short* __restrict__ Xg,
    const unsigned short* __restrict__ w1q, const unsigned short* __restrict__ w2q,
    const float* __restrict__ b1, const float* __restrict__ b2,
    unsigned short* __restrict__ actq, const int* __restrict__ np,
    const int* __restrict__ pexpP, const int* __restrict__ pm0P, const int* __restrict__ pendP,
    const int* __restrict__ pexpS, const int* __restrict__ pm0S, const int* __restrict__ pendS,
    int q)
{
  // chunked XCD swizzle, yc-fastest within chunk
  const int flat = blockIdx.y * FGX + blockIdx.x;
  const int CPX = (FGX * FGY) / 8;
  const int L = (flat & 7) * CPX + (flat >> 3);
  const int pidx = L >> 4;
  const int yc = L & 15;
  const int nP = np[0], nS = np[1];
  int e, m0, mend;
  if (pidx < nP)            { e = pexpP[pidx]; m0 = pm0P[pidx]; mend = pendP[pidx]; }
  else if (pidx < nP + nS)  { int s = pidx - nP; e = pexpS[s]; m0 = pm0S[s]; mend = pendS[s]; }
  else return;

  __shared__ unsigned short As[BM * BK];   // 16 KB
  __shared__ unsigned short B1s[BN * BK];  // 8 KB
  __shared__ unsigned short B2s[BN * BK];  // 8 KB

  const int tid = threadIdx.x;
  const int wid = tid >> 6, lane = tid & 63;
  const int wr = wid >> 1, wc = wid & 1;   // 2x2 waves: 64 rows x 32 cols each
  const int fr = lane & 15;
  const int fq = lane >> 4;

  const unsigned short* Bbase1 = w1q + ((size_t)e * HQ + yc * BN) * DDIM;
  const unsigned short* Bbase2 = w2q + ((size_t)e * HQ + yc * BN) * DDIM;

  f32x4 acc1[4][2] = {};
  f32x4 acc2[4][2] = {};

  for (int kt = 0; kt < DDIM / BK; ++kt) {
    if (kt > 0) __syncthreads();
    const int k0 = kt * BK;
    #pragma unroll
    for (int it = 0; it < 4; ++it) {
      const int idx = it * 256 + tid;
      const int row = idx >> 3, seg = idx & 7;
      const int koff = ((seg ^ (row & 7)) << 3);
      gload16(&As[idx * 8], Xg + (size_t)(m0 + row) * DDIM + k0 + koff);
    }
    #pragma unroll
    for (int it = 0; it < 2; ++it) {
      const int idx = it * 256 + tid;
      const int row = idx >> 3, seg = idx & 7;
      const int koff = ((seg ^ (row & 7)) << 3);
      gload16(&B1s[idx * 8], Bbase1 + (size_t)row * DDIM + k0 + koff);
    }
    #pragma unroll
    for (int it = 0; it < 2; ++it) {
      const int idx = it * 256 + tid;
      const int row = idx >> 3, seg = idx & 7;
      const int koff = ((seg ^ (row & 7)) << 3);
      gload16(&B2s[idx * 8], Bbase2 + (size_t)row * DDIM + k0 + koff);
    }
    __syncthreads();

    #pragma unroll
    for (int kk = 0; kk < 2; ++kk) {
      bf16x8 av[4], b1v[2], b2v[2];
      #pragma unroll
      for (int mf = 0; mf < 4; ++mf) {
        const int row = wr * 64 + mf * 16 + fr;
        const int seg = (kk * 4 + fq) ^ (row & 7);
        av[mf] = *(const bf16x8*)&As[row * BK + seg * 8];
      }
      #pragma unroll
      for (int nf = 0; nf < 2; ++nf) {
        const int row = wc * 32 + nf * 16 + fr;
        const int seg = (kk * 4 + fq) ^ (row & 7);
        b1v[nf] = *(const bf16x8*)&B1s[row * BK + seg * 8];
        b2v[nf] = *(const bf16x8*)&B2s[row * BK + seg * 8];
      }
      #pragma unroll
      for (int mf = 0; mf < 4; ++mf)
        #pragma unroll
        for (int nf = 0; nf < 2; ++nf) {
          acc1[mf][nf] = mfma16(av[mf], b1v[nf], acc1[mf][nf]);
          acc2[mf][nf] = mfma16(av[mf], b2v[nf], acc2[mf][nf]);
        }
    }
  }

  // epilogue: C/D layout col=lane&15, row=(lane>>4)*4+j
  const int mcnt = mend - m0;
  #pragma unroll
  for (int mf = 0; mf < 4; ++mf) {
    const int rb = wr * 64 + mf * 16 + (fq << 2);
    #pragma unroll
    for (int nf = 0; nf < 2; ++nf) {
      const int cq = yc * BN + wc * 32 + nf * 16 + fr;      // col in quarter
      const float bb1 = b1[(size_t)e * HDIM + q * HQ + cq];
      const float bb2 = b2[(size_t)e * HDIM + q * HQ + cq];
      #pragma unroll
      for (int j = 0; j < 4; ++j) {
        const int lr = rb + j;
        if (lr < mcnt) {
          float h = acc1[mf][nf][j] + bb1;
          float g = acc2[mf][nf][j] + bb2;
          float s = g / (1.f + expf(-g));
          actq[(size_t)(m0 + lr) * HQ + cq] = f2bf(h * s);
        }
      }
    }
  }
}

// ---------------- down GEMM pass (grouped over one region's panels) ----------
// Y[tok, d] (=|+=) gate * (act@wp^T + bp), K = HQ = 1024
#define DGX 144
#define DGY 16
template<bool STORE>
__global__ __launch_bounds__(256, 2) void k_down(
    const unsigned short* __restrict__ actq, const unsigned short* __restrict__ wpq,
    const float* __restrict__ bp,
    const int* __restrict__ np, int npIdx,
    const int* __restrict__ pexp, const int* __restrict__ pm0, const int* __restrict__ pend,
    const int* __restrict__ rowtok, const float* __restrict__ rowgate,
    float* __restrict__ Y)
{
  const int flat = blockIdx.y * DGX + blockIdx.x;
  const int CPX = (DGX * DGY) / 8;
  const int L = (flat & 7) * CPX + (flat >> 3);
  const int pidx = L >> 4;
  const int yc = L & 15;
  if (pidx >= np[npIdx]) return;
  const int e = pexp[pidx], m0 = pm0[pidx], mend = pend[pidx];

  __shared__ unsigned short As[BM * BK];   // 16 KB
  __shared__ unsigned short Bs[BN * BK];   // 8 KB

  const int tid = threadIdx.x;
  const int wid = tid >> 6, lane = tid & 63;
  const int wr = wid >> 1, wc = wid & 1;
  const int fr = lane & 15;
  const int fq = lane >> 4;

  const unsigned short* Bbase = wpq + ((size_t)e * DDIM + yc * BN) * HQ;

  f32x4 acc[4][2] = {};

  for (int kt = 0; kt < HQ / BK; ++kt) {
    if (kt > 0) __syncthreads();
    const int k0 = kt * BK;
    #pragma unroll
    for (int it = 0; it < 4; ++it) {
      const int idx = it * 256 + tid;
      const int row = idx >> 3, seg = idx & 7;
      const int koff = ((seg ^ (row & 7)) << 3);
      gload16(&As[idx * 8], actq + (size_t)(m0 + row) * HQ + k0 + koff);
    }
    #pragma unroll
    for (int it = 0; it < 2; ++it) {
      const int idx = it * 256 + tid;
      const int row = idx >> 3, seg = idx & 7;
      const int koff = ((seg ^ (row & 7)) << 3);
      gload16(&Bs[idx * 8], Bbase + (size_t)row * HQ + k0 + koff);
    }
    __syncthreads();

    #pragma unroll
    for (int kk = 0; kk < 2; ++kk) {
      bf16x8 av[4], bv[2];
      #pragma unroll
      for (int mf = 0; mf < 4; ++mf) {
        const int row = wr * 64 + mf * 16 + fr;
        const int seg = (kk * 4 + fq) ^ (row & 7);
        av[mf] = *(const bf16x8*)&As[row * BK + seg * 8];
      }
      #pragma unroll
      for (int nf = 0; nf < 2; ++nf) {
        const int row = wc * 32 + nf * 16 + fr;
        const int seg = (kk * 4 + fq) ^ (row & 7);
        bv[nf] = *(const bf16x8*)&Bs[row * BK + seg * 8];
      }
      #pragma unroll
      for (int mf = 0; mf < 4; ++mf)
        #pragma unroll
        for (int nf = 0; nf < 2; ++nf)
          acc[mf][nf] = mfma16(av[mf], bv[nf], acc[mf][nf]);
    }
  }

  const int mcnt = mend - m0;
  #pragma unroll
  for (int mf = 0; mf < 4; ++mf) {
    const int rb = wr * 64 + mf * 16 + (fq << 2);
    #pragma unroll
    for (int nf = 0; nf < 2; ++nf) {
      const int dg = yc * BN + wc * 32 + nf * 16 + fr;
      const float bb = bp[(size_t)e * DDIM + dg];
      #pragma unroll
      for (int j = 0; j < 4; ++j) {
        const int lr = rb + j;
        if (lr < mcnt) {
          const int r = m0 + lr;
          const float o = rowgate[r] * (acc[mf][nf][j] + bb);
          float* yp = &Y[(size_t)rowtok[r] * DDIM + dg];
          if (STORE) *yp = o; else *yp += o;
        }
      }
    }
  }
}

extern "C" void kernel_launch(void* const* d_in, const int* in_sizes, int n_in,
                              void* d_out, int out_size, void* d_ws, size_t ws_size,
                              hipStream_t stream) {
  const float* x      = (const float*)d_in[0];
  const float* noise  = (const float*)d_in[1];
  const float* gate_w = (const float*)d_in[2];
  const float* nw     = (const float*)d_in[3];
  const float* w1     = (const float*)d_in[4];
  const float* b1     = (const float*)d_in[5];
  const float* w2     = (const float*)d_in[6];
  const float* b2     = (const float*)d_in[7];
  const float* wp     = (const float*)d_in[8];
  const float* bp     = (const float*)d_in[9];
  float* y = (float*)d_out;

  if (ws_size < WS_NEEDED) return;   // diagnostic: output stays poisoned

  char* ws = (char*)d_ws;
  float* gwsum   = (float*)(ws + OFF_GWSUM);
  int*   off16   = (int*)(ws + OFF_OFF16);
  int*   np      = (int*)(ws + OFF_NP);
  int*   blkcnt  = (int*)(ws + OFF_BLK);
  int*   gbase   = (int*)(ws + OFF_GBASE);
  int*   pexpP   = (int*)(ws + OFF_PEXPP);
  int*   pm0P    = (int*)(ws + OFF_PM0P);
  int*   pendP   = (int*)(ws + OFF_PENDP);
  int*   pexpS   = (int*)(ws + OFF_PEXPS);
  int*   pm0S    = (int*)(ws + OFF_PM0S);
  int*   pendS   = (int*)(ws + OFF_PENDS);
  int*   tope    = (int*)(ws + OFF_TOPE);
  float* topw    = (float*)(ws + OFF_TOPW);
  unsigned int* lrank = (unsigned int*)(ws + OFF_LRANK);
  int*   rowtok  = (int*)(ws + OFF_ROWTOK);
  float* rowgate = (float*)(ws + OFF_ROWG);
  unsigned short* Xg   = (unsigned short*)(ws + OFF_XG);
  unsigned short* actq = (unsigned short*)(ws + OFF_ACTQ);
  unsigned short* w1q  = (unsigned short*)(ws + OFF_W1Q);
  unsigned short* w2q  = (unsigned short*)(ws + OFF_W2Q);
  unsigned short* wpq  = (unsigned short*)(ws + OFF_WPQ);

  hipMemsetAsync(d_ws, 0, 64, stream);   // gwsum only

  k_gate<<<T_TOK / 4, 256, 0, stream>>>(x, noise, gate_w, nw, gwsum, tope, topw);
  k_hist<<<T_TOK / 256, 256, 0, stream>>>(tope, lrank, blkcnt);
  k_scan<<<1, 512, 0, stream>>>(blkcnt, gbase, off16, np,
                                pexpP, pm0P, pendP, pexpS, pm0S, pendS,
                                gwsum, y + (size_t)T_TOK * DDIM);
  k_copy<<<T_TOK / 4, 256, 0, stream>>>(x, tope, topw, lrank, gbase,
                                        rowtok, rowgate, Xg);

  for (int q = 0; q < NQ; ++q) {
    k_castup<<<2048, 256, 0, stream>>>(w1, w2, w1q, w2q, q);
    k_castdn<<<1024, 256, 0, stream>>>(wp, wpq, q);
    k_fused<<<dim3(FGX, FGY), 256, 0, stream>>>(
        Xg, w1q, w2q, b1, b2, actq, np,
        pexpP, pm0P, pendP, pexpS, pm0S, pendS, q);
    if (q == 0)
      k_down<true><<<dim3(DGX, DGY), 256, 0, stream>>>(
          actq, wpq, bp, np, 0, pexpP, pm0P, pendP, rowtok, rowgate, y);
    else
      k_down<false><<<dim3(DGX, DGY), 256, 0, stream>>>(
          actq, wpq, bp, np, 0, pexpP, pm0P, pendP, rowtok, rowgate, y);
    k_down<false><<<dim3(DGX, DGY), 256, 0, stream>>>(
        actq, wpq, bp, np, 1, pexpS, pm0S, pendS, rowtok, rowgate, y);
  }
}